// Round 1
// baseline (476.398 us; speedup 1.0000x reference)
//
#include <hip/hip_runtime.h>

#define Bn 512
#define Ln 2048
#define Kn 19
#define NEGV (-1000.0f)
#define START_IDn 17
#define PAD_IDn 18
#define SEG 64               // checkpoint / staging segment (steps)
#define PBYTES 79691776u     // 512*2048*19*4

// ---------------------------------------------------------------------------
// R6: crf_fwd redesigned — 1 batch per wave64, dp broadcast via v_readlane
// into SGPRs instead of an LDS write->read round trip. The serial per-step
// chain is now register/SGPR-only (~49 VALU instrs, no LDS in the dependent
// path). Theory: step time drops from ~280 cy (LDS-latency-bound) to
// ~125-150 cy (issue-bound). crf_rec / crf_bwd unchanged (max is exactly
// associative, so DP values are bit-identical regardless of reduction shape).
// ---------------------------------------------------------------------------

// Shared per-step core for crf_rec: cand[p] = dp[p] + Trow[p] read from LDS.
#define DP_CORE(BASE)                                                          \
    float4 q0 = *(const float4*)((BASE) + 0);                                  \
    float4 q1 = *(const float4*)((BASE) + 4);                                  \
    float4 q2 = *(const float4*)((BASE) + 8);                                  \
    float4 q3 = *(const float4*)((BASE) + 12);                                 \
    float4 q4 = *(const float4*)((BASE) + 16); /* .w junk, unused */           \
    float cand[Kn];                                                            \
    cand[0]  = q0.x + Trow[0];  cand[1]  = q0.y + Trow[1];                     \
    cand[2]  = q0.z + Trow[2];  cand[3]  = q0.w + Trow[3];                     \
    cand[4]  = q1.x + Trow[4];  cand[5]  = q1.y + Trow[5];                     \
    cand[6]  = q1.z + Trow[6];  cand[7]  = q1.w + Trow[7];                     \
    cand[8]  = q2.x + Trow[8];  cand[9]  = q2.y + Trow[9];                     \
    cand[10] = q2.z + Trow[10]; cand[11] = q2.w + Trow[11];                    \
    cand[12] = q3.x + Trow[12]; cand[13] = q3.y + Trow[13];                    \
    cand[14] = q3.z + Trow[14]; cand[15] = q3.w + Trow[15];                    \
    cand[16] = q4.x + Trow[16]; cand[17] = q4.y + Trow[17];                    \
    cand[18] = q4.z + Trow[18];                                                \
    float m0 = fmaxf(fmaxf(cand[0],  cand[1]),  cand[2]);                      \
    float m1 = fmaxf(fmaxf(cand[3],  cand[4]),  cand[5]);                      \
    float m2 = fmaxf(fmaxf(cand[6],  cand[7]),  cand[8]);                      \
    float m3 = fmaxf(fmaxf(cand[9],  cand[10]), cand[11]);                     \
    float m4 = fmaxf(fmaxf(cand[12], cand[13]), cand[14]);                     \
    float m5 = fmaxf(fmaxf(cand[15], cand[16]), cand[17]);                     \
    float n0 = fmaxf(fmaxf(m0, m1), m2);                                       \
    float n1 = fmaxf(fmaxf(m3, m4), cand[18]);                                 \
    float best = fmaxf(fmaxf(n0, n1), m5);

// Forward-only core: dp broadcast lane->SGPR via readlane (wave-uniform),
// cand add is v_add_f32 v,s,v. No LDS in the dependent chain.
#define FWD_CORE()                                                             \
    float cand[Kn];                                                            \
    _Pragma("unroll")                                                          \
    for (int p_ = 0; p_ < Kn; ++p_) {                                          \
        float s_ = __uint_as_float(                                            \
            __builtin_amdgcn_readlane(__float_as_uint(mydp), p_));             \
        cand[p_] = s_ + Trow[p_];                                              \
    }                                                                          \
    float m0 = fmaxf(fmaxf(cand[0],  cand[1]),  cand[2]);                      \
    float m1 = fmaxf(fmaxf(cand[3],  cand[4]),  cand[5]);                      \
    float m2 = fmaxf(fmaxf(cand[6],  cand[7]),  cand[8]);                      \
    float m3 = fmaxf(fmaxf(cand[9],  cand[10]), cand[11]);                     \
    float m4 = fmaxf(fmaxf(cand[12], cand[13]), cand[14]);                     \
    float m5 = fmaxf(fmaxf(cand[15], cand[16]), cand[17]);                     \
    float n0 = fmaxf(fmaxf(m0, m1), m2);                                       \
    float n1 = fmaxf(fmaxf(m3, m4), cand[18]);                                 \
    float best = fmaxf(fmaxf(n0, n1), m5);

// ---------------------------------------------------------------------------
__global__ __launch_bounds__(64, 1) void crf_fwd(
    const float* __restrict__ P, const float* __restrict__ T,
    const int* __restrict__ mask, float* __restrict__ dpck,
    float* __restrict__ dpfin, int* __restrict__ lens)
{
    const int lane = threadIdx.x;
    const int b = blockIdx.x;                 // 1 batch per wave64
    const int cc = (lane < Kn) ? lane : (Kn - 1);

    float Trow[Kn];
#pragma unroll
    for (int p = 0; p < Kn; ++p) Trow[p] = T[cc * Kn + p];

    // length = popcount of contiguous-prefix mask row (64 lanes x int4 x 8)
    const int* mrow = mask + (size_t)b * Ln;
    int sum = 0;
#pragma unroll
    for (int j = 0; j < Ln / 256; ++j) {
        int4 v = *(const int4*)(mrow + j * 256 + lane * 4);
        sum += v.x + v.y + v.z + v.w;
    }
#pragma unroll
    for (int k = 1; k < 64; k <<= 1) sum += __shfl_xor(sum, k, 64);
    int len = __builtin_amdgcn_readfirstlane(sum);   // wave-uniform scalar
    if (lane == 0) lens[b] = len;
    const int mlen = (len + (SEG - 1)) & ~(SEG - 1);

    // emissions double-buffer: SEG*19 = 1216 floats used, 1280 staged
    __shared__ float ebuf[2][1280];

    float mydp = (lane == START_IDn) ? 0.0f : NEGV;

    const unsigned bbyte = (unsigned)b * (Ln * Kn * 4u);
    const unsigned limit = PBYTES - 16;
    const char* Pc = (const char*)P;
    float4 r[5];

#define STAGE_LOAD(ci)                                                         \
    { unsigned base_ = bbyte + (unsigned)(ci) * 4864u + ((unsigned)lane << 4); \
      _Pragma("unroll")                                                        \
      for (int i_ = 0; i_ < 5; ++i_) {                                         \
          unsigned o_ = base_ + (unsigned)i_ * 1024u;                          \
          if (o_ > limit) o_ = limit;                                          \
          r[i_] = *(const float4*)(Pc + o_);                                   \
      } }
#define STAGE_WRITE(nb)                                                        \
    { float* d_ = &ebuf[nb][(unsigned)lane << 2];                              \
      _Pragma("unroll")                                                        \
      for (int i_ = 0; i_ < 5; ++i_) *(float4*)(d_ + i_ * 256) = r[i_]; }

    int buf = 0;
    STAGE_LOAD(0);
    STAGE_WRITE(0);

    for (int t0 = 0; t0 < mlen; t0 += SEG) {
        // checkpoint: DP entering step t0 (includes initial DP at t0=0)
        if (lane < Kn)
            dpck[((unsigned)b * 32u + (unsigned)(t0 >> 6)) * (unsigned)Kn + (unsigned)lane] = mydp;
        STAGE_LOAD((t0 >> 6) + 1);       // prefetch next segment's emissions
        const float* ebl = &ebuf[buf][0];

        if (t0 + SEG <= len) {
            // fast path: every step strictly below len — no mask select
            for (int tt = 0; tt < SEG; tt += 8) {
#pragma unroll
                for (int u = 0; u < 8; ++u) {
                    const float e = ebl[(tt + u) * Kn + cc];
                    FWD_CORE()
                    mydp = best + e;
                }
            }
        } else {
            for (int tt = 0; tt < SEG; tt += 8) {
#pragma unroll
                for (int u = 0; u < 8; ++u) {
                    const int t = t0 + tt + u;
                    const float e = ebl[(tt + u) * Kn + cc];
                    FWD_CORE()
                    float nd = best + e;
                    mydp = (t < len) ? nd : mydp;   // len uniform -> scalar cond
                }
            }
        }
        STAGE_WRITE(buf ^ 1);
        buf ^= 1;
    }
    if (lane < Kn) dpfin[b * Kn + lane] = mydp;
#undef STAGE_LOAD
#undef STAGE_WRITE
}

// ---------------------------------------------------------------------------
// Recompute backpointers: task = (batch, segment); 32-lane half-wave per task,
// 8 tasks per 256-thread block. High occupancy hides all latencies; the DP
// values recomputed here are bit-identical to crf_fwd (same adds; max is
// exactly associative), so argmax reproduces the reference backpointers.
// ---------------------------------------------------------------------------
__global__ __launch_bounds__(256) void crf_rec(
    const float* __restrict__ P, const float* __restrict__ T,
    const float* __restrict__ dpck, const int* __restrict__ lens,
    unsigned char* __restrict__ choice)
{
    const int tid = threadIdx.x;
    const int halfid = tid >> 5;
    const int c = tid & 31;
    const int cc = (c < Kn) ? c : (Kn - 1);
    const int task = blockIdx.x * 8 + halfid;   // < 16384
    const int b = task >> 5;
    const int seg = task & 31;
    const int t0 = seg * SEG;
    const int len = lens[b];
    if (t0 >= len) return;                      // rows never read by backtrace

    __shared__ float dp[8][32];
    __shared__ __align__(16) unsigned char cbuf[8][SEG * Kn];  // 8 x 1216

    float Trow[Kn];
#pragma unroll
    for (int p = 0; p < Kn; ++p) Trow[p] = T[cc * Kn + p];

    float mydp = (c < Kn) ? dpck[((unsigned)b * 32u + (unsigned)seg) * (unsigned)Kn + (unsigned)c]
                          : NEGV;
    dp[halfid][c] = mydp;

    const float* prow = P + (size_t)b * Ln * Kn + (size_t)t0 * Kn;

    // rolling emission prefetch (depth 8)
    float eb[8];
#pragma unroll
    for (int u = 0; u < 8; ++u) eb[u] = prow[u * Kn + cc];

    for (int tt = 0; tt < SEG; tt += 8) {
#pragma unroll
        for (int u = 0; u < 8; ++u) {
            const int t = t0 + tt + u;
            const float e = eb[u];
            const float* base_ = &dp[halfid][0];
            DP_CORE(base_)
            float nd = best + e;
            mydp = (t < len) ? nd : mydp;
            dp[halfid][c] = mydp;

            // first-index argmax (jnp.argmax tie-break), exact equality
            int arg = Kn - 1;
#pragma unroll
            for (int p = Kn - 2; p >= 0; --p)
                arg = (cand[p] == best) ? p : arg;
            if (c < Kn) cbuf[halfid][(tt + u) * Kn + c] = (unsigned char)arg;

            // prefetch emission for local step tt+u+8 (clamped in-bounds)
            int tn = tt + u + 8;
            int tloc = (t0 + tn < Ln) ? tn : (Ln - 1 - t0);
            eb[u] = prow[tloc * Kn + cc];
        }
    }
    // bulk flush this segment's backpointers (steps >= len garbage, unread)
    {
        const int4* s = (const int4*)&cbuf[halfid][0];
        int4* d = (int4*)(choice + (size_t)b * Ln * Kn + (size_t)t0 * Kn);
        for (int i = c; i < (SEG * Kn) / 16; i += 32) d[i] = s[i];
    }
}

// ---------------------------------------------------------------------------
// Backtrace: unchanged (exact integer function-composition scan).
// ---------------------------------------------------------------------------
__global__ __launch_bounds__(384, 1) void crf_bwd(
    const float* __restrict__ T, const unsigned char* __restrict__ choice,
    const float* __restrict__ dpfin, const int* __restrict__ lens,
    int* __restrict__ out)
{
    __shared__ unsigned char comp[Ln * Kn];   // 38912 B
    __shared__ int vchain[17];
    __shared__ int s_last, s_len;

    const int b = blockIdx.x;
    const int tid = threadIdx.x;

    {
        const int4* src = (const int4*)(choice + (size_t)b * Ln * Kn);
        int4* dst = (int4*)comp;
        for (int i = tid; i < (Ln * Kn) / 16; i += 384) dst[i] = src[i];
    }
    if (tid == 0) {
        s_len = lens[b];
        float bestv = dpfin[b * Kn + 0] + T[PAD_IDn * Kn + 0];
        int bl = 0;
        for (int ci = 1; ci < Kn; ++ci) {
            float v = dpfin[b * Kn + ci] + T[PAD_IDn * Kn + ci];
            if (v > bestv) { bestv = v; bl = ci; }
        }
        s_last = bl;
    }
    __syncthreads();
    const int len = s_len;

    // Phase 1: suffix-compose within each 128-step chunk, in place.
    // Rows t >= len compose to identity (g_t = id), so garbage in those
    // choice rows is read-then-discarded, never propagated.
    {
        const int wv = tid >> 6;
        const int lane = tid & 63;
        const int ch = wv * 3 + lane / Kn;
        const int c = lane % Kn;
        if (lane < 3 * Kn && ch < 16) {
            int cur = c;
            const int tb = ch * 128 + 127;
            for (int i = 0; i < 128; ++i) {
                const int t = tb - i;
                int nv = comp[t * Kn + cur];   // cur <= 18 always: in-bounds
                cur = (t < len) ? nv : cur;
                comp[t * Kn + c] = cur;
            }
        }
    }
    __syncthreads();

    // Phase 2: chunk-boundary chain
    if (tid == 0) {
        int v = s_last;
        vchain[16] = v;
        for (int ch = 15; ch >= 0; --ch) {
            v = comp[ch * 128 * Kn + v];
            vchain[ch] = v;
        }
    }
    __syncthreads();

    // Phase 3: emit path
    const int last = s_last;
    int* orow = out + (size_t)b * Ln;
    for (int t = tid; t < Ln; t += 384) {
        int val;
        if (t >= len) {
            val = -1;
        } else if (t == Ln - 1) {
            val = last;
        } else {
            const int tp = t + 1;
            const int vc = vchain[(tp >> 7) + 1];
            val = comp[tp * Kn + vc];
        }
        orow[t] = val;
    }
}

// ---------------------------------------------------------------------------
extern "C" void kernel_launch(void* const* d_in, const int* in_sizes, int n_in,
                              void* d_out, int out_size, void* d_ws, size_t ws_size,
                              hipStream_t stream)
{
    const float* P    = (const float*)d_in[0];
    const float* T    = (const float*)d_in[1];
    const int*   mask = (const int*)d_in[2];
    int* out = (int*)d_out;

    // workspace layout — identical footprint to R1-R3 (19,963,904 B proven ok)
    const size_t choice_bytes = (size_t)Bn * Ln * Kn;            // 19,922,944
    unsigned char* choice = (unsigned char*)d_ws;
    float* dpfin = (float*)((char*)d_ws + choice_bytes);         // 38,912 B
    int* lens = (int*)((char*)d_ws + choice_bytes + (size_t)Bn * Kn * 4);

    // dpck (1,245,184 B) lives in d_out (4 MB): written by crf_fwd, read by
    // crf_rec, then d_out is fully overwritten by crf_bwd. Stream-ordered.
    float* dpck = (float*)((char*)d_out + 2 * 1024 * 1024);

    crf_fwd<<<Bn, 64, 0, stream>>>(P, T, mask, dpck, dpfin, lens);
    crf_rec<<<(Bn * 32) / 8, 256, 0, stream>>>(P, T, dpck, lens, choice);
    crf_bwd<<<Bn, 384, 0, stream>>>(T, choice, dpfin, lens, out);
}

// Round 2
// 449.905 us; speedup vs baseline: 1.0589x; 1.0589x over previous
//
#include <hip/hip_runtime.h>

#define Bn 512
#define Ln 2048
#define Kn 19
#define NEGV (-1000.0f)
#define START_IDn 17
#define PAD_IDn 18
#define SEG 64               // checkpoint / staging segment (steps)
#define PBYTES 79691776u     // 512*2048*19*4

// ---------------------------------------------------------------------------
// R7: crf_fwd broadcast via ds_swizzle_b32 (BitMode or-broadcast, imm offset
// p<<5): each lane pulls dp[p] straight from lane p's REGISTER through the
// LDS crossbar — no ds_write, no write->read in-order serialization (R5's
// chain), no VALU->SGPR hazards (R6's failure). 2 batches per wave (32-lane
// halves), swizzle is 32-group-local so one instruction serves both.
// Chain/step: 19 indep swizzles (issue burst) + 1 LDS-pipe latency + add +
// depth-3 max3 tree + e-add ~= 150-230 cy vs R5's 280 / R6's 369.
// crf_rec / crf_bwd unchanged (max exact => checkpoints bit-identical).
// ---------------------------------------------------------------------------

// crf_rec per-step core (unchanged): dp read from LDS, occupancy hides it.
#define DP_CORE(BASE)                                                          \
    float4 q0 = *(const float4*)((BASE) + 0);                                  \
    float4 q1 = *(const float4*)((BASE) + 4);                                  \
    float4 q2 = *(const float4*)((BASE) + 8);                                  \
    float4 q3 = *(const float4*)((BASE) + 12);                                 \
    float4 q4 = *(const float4*)((BASE) + 16); /* .w junk, unused */           \
    float cand[Kn];                                                            \
    cand[0]  = q0.x + Trow[0];  cand[1]  = q0.y + Trow[1];                     \
    cand[2]  = q0.z + Trow[2];  cand[3]  = q0.w + Trow[3];                     \
    cand[4]  = q1.x + Trow[4];  cand[5]  = q1.y + Trow[5];                     \
    cand[6]  = q1.z + Trow[6];  cand[7]  = q1.w + Trow[7];                     \
    cand[8]  = q2.x + Trow[8];  cand[9]  = q2.y + Trow[9];                     \
    cand[10] = q2.z + Trow[10]; cand[11] = q2.w + Trow[11];                    \
    cand[12] = q3.x + Trow[12]; cand[13] = q3.y + Trow[13];                    \
    cand[14] = q3.z + Trow[14]; cand[15] = q3.w + Trow[15];                    \
    cand[16] = q4.x + Trow[16]; cand[17] = q4.y + Trow[17];                    \
    cand[18] = q4.z + Trow[18];                                                \
    float m0 = fmaxf(fmaxf(cand[0],  cand[1]),  cand[2]);                      \
    float m1 = fmaxf(fmaxf(cand[3],  cand[4]),  cand[5]);                      \
    float m2 = fmaxf(fmaxf(cand[6],  cand[7]),  cand[8]);                      \
    float m3 = fmaxf(fmaxf(cand[9],  cand[10]), cand[11]);                     \
    float m4 = fmaxf(fmaxf(cand[12], cand[13]), cand[14]);                     \
    float m5 = fmaxf(fmaxf(cand[15], cand[16]), cand[17]);                     \
    float n0 = fmaxf(fmaxf(m0, m1), m2);                                       \
    float n1 = fmaxf(fmaxf(m3, m4), cand[18]);                                 \
    float best = fmaxf(fmaxf(n0, n1), m5);

// Register->register broadcast of lane p's mydp to all lanes of its 32-group.
// BitMode offset = (xor<<10)|(or<<5)|and ; and=0, or=p, xor=0  ->  p<<5.
#define SWZ(p) (__uint_as_float((unsigned)__builtin_amdgcn_ds_swizzle(         \
                    (int)__float_as_uint(mydp), ((p) << 5))))

// Forward core: produces `best` from mydp (cross-lane) + Trow. No LDS dp.
#define FWD_CAND()                                                             \
    float cand[Kn];                                                            \
    cand[0]  = SWZ(0)  + Trow[0];  cand[1]  = SWZ(1)  + Trow[1];               \
    cand[2]  = SWZ(2)  + Trow[2];  cand[3]  = SWZ(3)  + Trow[3];               \
    cand[4]  = SWZ(4)  + Trow[4];  cand[5]  = SWZ(5)  + Trow[5];               \
    cand[6]  = SWZ(6)  + Trow[6];  cand[7]  = SWZ(7)  + Trow[7];               \
    cand[8]  = SWZ(8)  + Trow[8];  cand[9]  = SWZ(9)  + Trow[9];               \
    cand[10] = SWZ(10) + Trow[10]; cand[11] = SWZ(11) + Trow[11];              \
    cand[12] = SWZ(12) + Trow[12]; cand[13] = SWZ(13) + Trow[13];              \
    cand[14] = SWZ(14) + Trow[14]; cand[15] = SWZ(15) + Trow[15];              \
    cand[16] = SWZ(16) + Trow[16]; cand[17] = SWZ(17) + Trow[17];              \
    cand[18] = SWZ(18) + Trow[18];                                             \
    float m0 = fmaxf(fmaxf(cand[0],  cand[1]),  cand[2]);                      \
    float m1 = fmaxf(fmaxf(cand[3],  cand[4]),  cand[5]);                      \
    float m2 = fmaxf(fmaxf(cand[6],  cand[7]),  cand[8]);                      \
    float m3 = fmaxf(fmaxf(cand[9],  cand[10]), cand[11]);                     \
    float m4 = fmaxf(fmaxf(cand[12], cand[13]), cand[14]);                     \
    float m5 = fmaxf(fmaxf(cand[15], cand[16]), cand[17]);                     \
    float n0 = fmaxf(fmaxf(m0, m1), m2);                                       \
    float n1 = fmaxf(fmaxf(m3, m4), cand[18]);                                 \
    float best = fmaxf(fmaxf(n0, n1), m5);

// ---------------------------------------------------------------------------
__global__ __launch_bounds__(64, 1) void crf_fwd(
    const float* __restrict__ P, const float* __restrict__ T,
    const int* __restrict__ mask, float* __restrict__ dpck,
    float* __restrict__ dpfin, int* __restrict__ lens)
{
    const int lane = threadIdx.x;
    const int half = lane >> 5;
    const int c = lane & 31;
    const int b = blockIdx.x * 2 + half;
    const int cc = (c < Kn) ? c : (Kn - 1);

    float Trow[Kn];
#pragma unroll
    for (int p = 0; p < Kn; ++p) Trow[p] = T[cc * Kn + p];

    // length = popcount of contiguous-prefix mask row (per half)
    const int* mrow = mask + (size_t)b * Ln;
    int sum = 0;
#pragma unroll
    for (int j = 0; j < Ln / 128; ++j) {
        int4 v = *(const int4*)(mrow + j * 128 + c * 4);
        sum += v.x + v.y + v.z + v.w;
    }
#pragma unroll
    for (int k = 1; k < 32; k <<= 1) sum += __shfl_xor(sum, k, 64);
    const int len = sum;
    if (c == 0) lens[b] = len;
    const int lenO = __shfl_xor(len, 32, 64);
    int maxlen = len > lenO ? len : lenO;
    int lmin = len < lenO ? len : lenO;
    lmin = __builtin_amdgcn_readfirstlane(lmin);
    int mlen = (maxlen + (SEG - 1)) & ~(SEG - 1);
    mlen = __builtin_amdgcn_readfirstlane(mlen);

    __shared__ float ebuf[2][2][1280];   // [buf][half]; 64*19=1216 used + pad

    float mydp = (c == START_IDn) ? 0.0f : NEGV;

    const unsigned bbyte = (unsigned)b * (Ln * Kn * 4u);
    const unsigned limit = PBYTES - 16;
    const char* Pc = (const char*)P;
    float4 r[10];

#define STAGE_LOAD(ci)                                                         \
    { unsigned base_ = bbyte + (unsigned)(ci) * 4864u + ((unsigned)c << 4);    \
      _Pragma("unroll")                                                        \
      for (int i_ = 0; i_ < 10; ++i_) {                                        \
          unsigned o_ = base_ + (unsigned)i_ * 512u;                           \
          if (o_ > limit) o_ = limit;                                          \
          r[i_] = *(const float4*)(Pc + o_);                                   \
      } }
#define STAGE_WRITE(nb)                                                        \
    { float* d_ = &ebuf[nb][half][(unsigned)c << 2];                           \
      _Pragma("unroll")                                                        \
      for (int i_ = 0; i_ < 10; ++i_) *(float4*)(d_ + i_ * 128) = r[i_]; }

    int buf = 0;
    STAGE_LOAD(0);
    STAGE_WRITE(0);

    for (int t0 = 0; t0 < mlen; t0 += SEG) {
        // checkpoint: DP entering step t0 (includes initial DP at t0=0)
        if (c < Kn)
            dpck[((unsigned)b * 32u + (unsigned)(t0 >> 6)) * (unsigned)Kn + (unsigned)c] = mydp;
        STAGE_LOAD((t0 >> 6) + 1);       // prefetch next segment's emissions
        const float* ebl = &ebuf[buf][half][0];

        if (t0 + SEG <= lmin) {
            // fast path: every step strictly below both lengths — no mask
            for (int tt = 0; tt < SEG; tt += 8) {
#pragma unroll
                for (int u = 0; u < 8; ++u) {
                    const float e = ebl[(tt + u) * Kn + cc];
                    FWD_CAND()
                    mydp = best + e;
                }
            }
        } else {
            for (int tt = 0; tt < SEG; tt += 8) {
#pragma unroll
                for (int u = 0; u < 8; ++u) {
                    const int t = t0 + tt + u;
                    const float e = ebl[(tt + u) * Kn + cc];
                    FWD_CAND()
                    float nd = best + e;
                    mydp = (t < len) ? nd : mydp;   // frozen past sequence end
                }
            }
        }
        STAGE_WRITE(buf ^ 1);
        buf ^= 1;
    }
    if (c < Kn) dpfin[b * Kn + c] = mydp;
#undef STAGE_LOAD
#undef STAGE_WRITE
}

// ---------------------------------------------------------------------------
// Recompute backpointers: task = (batch, segment); 32-lane half-wave per task,
// 8 tasks per 256-thread block. High occupancy hides all latencies; per-step
// math is bit-identical to crf_fwd (same add pairs, max exact), so argmax
// reproduces the exact backpointers of a fully-serial run.
// ---------------------------------------------------------------------------
__global__ __launch_bounds__(256) void crf_rec(
    const float* __restrict__ P, const float* __restrict__ T,
    const float* __restrict__ dpck, const int* __restrict__ lens,
    unsigned char* __restrict__ choice)
{
    const int tid = threadIdx.x;
    const int halfid = tid >> 5;
    const int c = tid & 31;
    const int cc = (c < Kn) ? c : (Kn - 1);
    const int task = blockIdx.x * 8 + halfid;   // < 16384
    const int b = task >> 5;
    const int seg = task & 31;
    const int t0 = seg * SEG;
    const int len = lens[b];
    if (t0 >= len) return;                      // rows never read by backtrace

    __shared__ float dp[8][32];
    __shared__ __align__(16) unsigned char cbuf[8][SEG * Kn];  // 8 x 1216

    float Trow[Kn];
#pragma unroll
    for (int p = 0; p < Kn; ++p) Trow[p] = T[cc * Kn + p];

    float mydp = (c < Kn) ? dpck[((unsigned)b * 32u + (unsigned)seg) * (unsigned)Kn + (unsigned)c]
                          : NEGV;
    dp[halfid][c] = mydp;

    const float* prow = P + (size_t)b * Ln * Kn + (size_t)t0 * Kn;

    // rolling emission prefetch (depth 8)
    float eb[8];
#pragma unroll
    for (int u = 0; u < 8; ++u) eb[u] = prow[u * Kn + cc];

    for (int tt = 0; tt < SEG; tt += 8) {
#pragma unroll
        for (int u = 0; u < 8; ++u) {
            const int t = t0 + tt + u;
            const float e = eb[u];
            const float* base_ = &dp[halfid][0];
            DP_CORE(base_)
            float nd = best + e;
            mydp = (t < len) ? nd : mydp;
            dp[halfid][c] = mydp;

            // first-index argmax (jnp.argmax tie-break), exact equality
            int arg = Kn - 1;
#pragma unroll
            for (int p = Kn - 2; p >= 0; --p)
                arg = (cand[p] == best) ? p : arg;
            if (c < Kn) cbuf[halfid][(tt + u) * Kn + c] = (unsigned char)arg;

            // prefetch emission for local step tt+u+8 (clamped in-bounds)
            int tn = tt + u + 8;
            int tloc = (t0 + tn < Ln) ? tn : (Ln - 1 - t0);
            eb[u] = prow[tloc * Kn + cc];
        }
    }
    // bulk flush this segment's backpointers (steps >= len garbage, unread)
    {
        const int4* s = (const int4*)&cbuf[halfid][0];
        int4* d = (int4*)(choice + (size_t)b * Ln * Kn + (size_t)t0 * Kn);
        for (int i = c; i < (SEG * Kn) / 16; i += 32) d[i] = s[i];
    }
}

// ---------------------------------------------------------------------------
// Backtrace: unchanged (exact integer function-composition scan).
// ---------------------------------------------------------------------------
__global__ __launch_bounds__(384, 1) void crf_bwd(
    const float* __restrict__ T, const unsigned char* __restrict__ choice,
    const float* __restrict__ dpfin, const int* __restrict__ lens,
    int* __restrict__ out)
{
    __shared__ unsigned char comp[Ln * Kn];   // 38912 B
    __shared__ int vchain[17];
    __shared__ int s_last, s_len;

    const int b = blockIdx.x;
    const int tid = threadIdx.x;

    {
        const int4* src = (const int4*)(choice + (size_t)b * Ln * Kn);
        int4* dst = (int4*)comp;
        for (int i = tid; i < (Ln * Kn) / 16; i += 384) dst[i] = src[i];
    }
    if (tid == 0) {
        s_len = lens[b];
        float bestv = dpfin[b * Kn + 0] + T[PAD_IDn * Kn + 0];
        int bl = 0;
        for (int ci = 1; ci < Kn; ++ci) {
            float v = dpfin[b * Kn + ci] + T[PAD_IDn * Kn + ci];
            if (v > bestv) { bestv = v; bl = ci; }
        }
        s_last = bl;
    }
    __syncthreads();
    const int len = s_len;

    // Phase 1: suffix-compose within each 128-step chunk, in place.
    // Rows t >= len compose to identity (g_t = id), so garbage in those
    // choice rows is read-then-discarded, never propagated.
    {
        const int wv = tid >> 6;
        const int lane = tid & 63;
        const int ch = wv * 3 + lane / Kn;
        const int c = lane % Kn;
        if (lane < 3 * Kn && ch < 16) {
            int cur = c;
            const int tb = ch * 128 + 127;
            for (int i = 0; i < 128; ++i) {
                const int t = tb - i;
                int nv = comp[t * Kn + cur];   // cur <= 18 always: in-bounds
                cur = (t < len) ? nv : cur;
                comp[t * Kn + c] = cur;
            }
        }
    }
    __syncthreads();

    // Phase 2: chunk-boundary chain
    if (tid == 0) {
        int v = s_last;
        vchain[16] = v;
        for (int ch = 15; ch >= 0; --ch) {
            v = comp[ch * 128 * Kn + v];
            vchain[ch] = v;
        }
    }
    __syncthreads();

    // Phase 3: emit path
    const int last = s_last;
    int* orow = out + (size_t)b * Ln;
    for (int t = tid; t < Ln; t += 384) {
        int val;
        if (t >= len) {
            val = -1;
        } else if (t == Ln - 1) {
            val = last;
        } else {
            const int tp = t + 1;
            const int vc = vchain[(tp >> 7) + 1];
            val = comp[tp * Kn + vc];
        }
        orow[t] = val;
    }
}

// ---------------------------------------------------------------------------
extern "C" void kernel_launch(void* const* d_in, const int* in_sizes, int n_in,
                              void* d_out, int out_size, void* d_ws, size_t ws_size,
                              hipStream_t stream)
{
    const float* P    = (const float*)d_in[0];
    const float* T    = (const float*)d_in[1];
    const int*   mask = (const int*)d_in[2];
    int* out = (int*)d_out;

    // workspace layout — identical footprint to R1-R3 (19,963,904 B proven ok)
    const size_t choice_bytes = (size_t)Bn * Ln * Kn;            // 19,922,944
    unsigned char* choice = (unsigned char*)d_ws;
    float* dpfin = (float*)((char*)d_ws + choice_bytes);         // 38,912 B
    int* lens = (int*)((char*)d_ws + choice_bytes + (size_t)Bn * Kn * 4);

    // dpck (1,245,184 B) lives in d_out (4 MB): written by crf_fwd, read by
    // crf_rec, then d_out is fully overwritten by crf_bwd. Stream-ordered.
    float* dpck = (float*)((char*)d_out + 2 * 1024 * 1024);

    crf_fwd<<<Bn / 2, 64, 0, stream>>>(P, T, mask, dpck, dpfin, lens);
    crf_rec<<<(Bn * 32) / 8, 256, 0, stream>>>(P, T, dpck, lens, choice);
    crf_bwd<<<Bn, 384, 0, stream>>>(T, choice, dpfin, lens, out);
}